// Round 7
// baseline (29430.350 us; speedup 1.0000x reference)
//
#include <hip/hip_runtime.h>
#include <hip/hip_fp16.h>

#define T_LEN 65536
#define FDIM  128
#define NGATE 512   // 4*F for layer-2 LSTM

typedef int iv4 __attribute__((ext_vector_type(4)));

// ---------- fast math helpers ----------
__device__ __forceinline__ float frcp(float x) { return __builtin_amdgcn_rcpf(x); }
#define LOG2E 1.4426950408889634f
__device__ __forceinline__ float sigmoid_f(float x) {
  return frcp(1.f + __builtin_amdgcn_exp2f(-LOG2E * x));
}

// ---------- DPP cross-lane ops ----------
template<int CTRL, int ROWM, int BANKM, bool BC>
__device__ __forceinline__ float dpp_mov0(float x) {
  return __int_as_float(
      __builtin_amdgcn_update_dpp(0, __float_as_int(x), CTRL, ROWM, BANKM, BC));
}
// quad_perm broadcast of quad-lane Q to all 4 lanes of the quad
template<int Q>
__device__ __forceinline__ float qbcast(float x) {
  return dpp_mov0<(Q | (Q << 2) | (Q << 4) | (Q << 6)), 0xF, 0xF, true>(x);
}
__device__ __forceinline__ float red8(float a) {
  a += dpp_mov0<0xB1, 0xF, 0xF, true>(a);   // quad_perm xor-1
  a += dpp_mov0<0x4E, 0xF, 0xF, true>(a);   // quad_perm xor-2
  a += dpp_mov0<0x114, 0xF, 0xA, true>(a);  // row_shr:4, banks 1&3
  return a;
}
__device__ __forceinline__ float red16(float a) {
  a += dpp_mov0<0x111, 0xF, 0xF, true>(a);
  a += dpp_mov0<0x112, 0xF, 0xF, true>(a);
  a += dpp_mov0<0x114, 0xF, 0xF, true>(a);
  a += dpp_mov0<0x118, 0xF, 0xF, true>(a);
  return a;
}

union H8 { uint4 u; __half h[8]; };

// barrier draining ONLY lgkm (LDS): no per-step vmcnt round-trip.
#define LDS_BARRIER() asm volatile("s_waitcnt lgkmcnt(0)\n\ts_barrier" ::: "memory")

// ---------------------------------------------------------------------------
// Phase A: per-unit gate precompute, stored as [T][128] x {i,f,g,o} f16 quads.
// ---------------------------------------------------------------------------
__global__ __launch_bounds__(512, 2)
void gx_kernel(const float* __restrict__ x, const float* __restrict__ Wih2,
               const float* __restrict__ bih2, const float* __restrict__ bhh2,
               __half* __restrict__ gx)
{
  __shared__ float xs[64 * FDIM];           // 32 KB tile of x
  const int tid  = threadIdx.x;
  const int lane = tid & 63;
  const int wave = tid >> 6;
  const int q    = lane & 7;
  const int pl   = lane >> 3;
  const int p    = wave * 8 + pl;
  const int u0   = 2 * p;

  float w[8][16];
  float bias[8];
#pragma unroll
  for (int j = 0; j < 8; ++j) {
    const int row = ((j >> 1) * 128) + u0 + (j & 1);   // j = {i0,i1,f0,f1,g0,g1,o0,o1}
    const int base = row * FDIM + q * 16;
#pragma unroll
    for (int k = 0; k < 16; ++k) w[j][k] = Wih2[base + k];
    bias[j] = bih2[row] + bhh2[row];
  }

  const int t0 = blockIdx.x * 64;
  const float4* xg = (const float4*)(x + (size_t)t0 * FDIM);
  float4* xs4 = (float4*)xs;
#pragma unroll
  for (int i = 0; i < 4; ++i) xs4[tid + i * 512] = xg[tid + i * 512];
  __syncthreads();

  for (int tt = 0; tt < 64; ++tt) {
    float hv[16];
    const float4* hv4 = (const float4*)(xs + tt * FDIM + q * 16);
    *(float4*)&hv[0]  = hv4[0];
    *(float4*)&hv[4]  = hv4[1];
    *(float4*)&hv[8]  = hv4[2];
    *(float4*)&hv[12] = hv4[3];

    float acc[8];
#pragma unroll
    for (int j = 0; j < 8; ++j) {
      float a = 0.f;
#pragma unroll
      for (int k = 0; k < 16; ++k) a = fmaf(w[j][k], hv[k], a);
      acc[j] = red8(a) + bias[j];
    }
    if (q == 4) {
      // store unit-major gate quads: unit u0 -> {i0,f0,g0,o0}, u0+1 -> {i1,f1,g1,o1}
      H8 pk;
      pk.h[0] = __float2half(acc[0]); pk.h[1] = __float2half(acc[2]);
      pk.h[2] = __float2half(acc[4]); pk.h[3] = __float2half(acc[6]);
      pk.h[4] = __float2half(acc[1]); pk.h[5] = __float2half(acc[3]);
      pk.h[6] = __float2half(acc[5]); pk.h[7] = __float2half(acc[7]);
      *((uint4*)(gx + ((size_t)(t0 + tt) * FDIM + u0) * 4)) = pk.u;
    }
  }
}

// ---------------------------------------------------------------------------
// Phase B: sequential LSTM-2 scan, int8 sdot4 + quad-DPP exchange,
// instruction-dieted. 512 threads, 8 waves (2/SIMD).
//   lane = 4*ul + g : quad = unit u = 16*wave + ul, g in {i,f,g,o}.
// Per-lane full W_hh2 row (32 dwords int8, per-row scale, exact int32 acc).
// Overhead removal:
//  - 8-step unroll makes the hq double-buffer index (s&1) compile-time ->
//    all ds_read_b128 / ds_write_b8 use immediate offsets off static bases.
//  - gx prefetch & hist store use uniform SGPR bases recomputed per step on
//    the scalar unit + a fixed per-lane 32-bit index (SADDR-form global ops).
//  - no exec masking: all 4 quad lanes write the same value to the same
//    hq byte / hist dword (same-address writes collapse).
// One lgkm-only barrier per step; hist store placed after the barrier.
// ---------------------------------------------------------------------------
__global__ __launch_bounds__(512)
void scan_kernel(const __half* __restrict__ gx, const float* __restrict__ Whh2,
                 const float* __restrict__ h20, const float* __restrict__ c20,
                 float* __restrict__ hist)
{
  __shared__ __align__(16) signed char hq[2][FDIM];   // int8 h, double-buffered

  const int tid  = threadIdx.x;
  const int lane = tid & 63;
  const int wave = tid >> 6;        // 0..7
  const int g    = lane & 3;        // gate {i,f,g,o} within the quad
  const int ul   = lane >> 2;       // 0..15
  const int u    = 16 * wave + ul;  // 0..127
  const int row  = g * FDIM + u;    // unique W_hh2 row per lane (512 total)

  // ---- init: quantize own W_hh2 row to int8 with per-row scale ----
  const float* wr = Whh2 + (size_t)row * FDIM;
  float m = 1e-20f;
#pragma unroll
  for (int k = 0; k < FDIM; k += 4) {
    const float4 v = *(const float4*)(wr + k);
    m = fmaxf(m, fmaxf(fmaxf(fabsf(v.x), fabsf(v.y)),
                       fmaxf(fabsf(v.z), fabsf(v.w))));
  }
  const float inv = 127.f / m;
  const float dq  = m * (1.f / 16129.f);    // m/127 * 1/127
  int wq[32];
#pragma unroll
  for (int d = 0; d < 32; ++d) {
    const float4 v = *(const float4*)(wr + 4 * d);
    int b0 = (int)rintf(v.x * inv), b1 = (int)rintf(v.y * inv);
    int b2 = (int)rintf(v.z * inv), b3 = (int)rintf(v.w * inv);
    b0 = b0 < -127 ? -127 : (b0 > 127 ? 127 : b0);
    b1 = b1 < -127 ? -127 : (b1 > 127 ? 127 : b1);
    b2 = b2 < -127 ? -127 : (b2 > 127 ? 127 : b2);
    b3 = b3 < -127 ? -127 : (b3 > 127 ? 127 : b3);
    wq[d] = (b0 & 255) | ((b1 & 255) << 8) | ((b2 & 255) << 16) | ((b3 & 255) << 24);
  }

  // lane-constant activation constants: gate 2 (g-gate) uses tanh = 2*sig(2x)-1
  const bool isg   = (g == 2);
  const float emul = isg ? (-2.f * LOG2E) : (-LOG2E);  // folds selm into exp2 arg
  const float selA = isg ? 2.f : 1.f;
  const float selB = isg ? -1.f : 0.f;

  float c = c20[u];                 // redundant across the 4 quad lanes
  if (tid < FDIM) {
    const float hv = fminf(fmaxf(h20[tid], -1.f), 1.f);
    hq[0][tid] = (signed char)(int)rintf(127.f * hv);
  }

  // static LDS bases: reads broadcast from hq[s&1][*]; writes to hq[(s+1)&1][u]
  const signed char* hrd = &hq[0][0];       // + imm (s&1)*128 + 16*r
  signed char*       hwr = &hq[0][0] + u;   // + imm ((s+1)&1)*128

  const unsigned short* gxh = (const unsigned short*)gx;  // 512 halfs per step
  const int goffh = u * 4 + g;              // fixed per-lane half-index

  unsigned short gpf[8];
#pragma unroll
  for (int s = 0; s < 8; ++s)
    gpf[s] = gxh[(size_t)s * 512 + goffh];  // steps 0..7

  __syncthreads();

  for (int t = 0; t < T_LEN; t += 8) {
#pragma unroll
    for (int s = 0; s < 8; ++s) {
      const int tt = t + s;

      // h_{t-1}: 8x ds_read_b128, compile-time offsets, broadcast address
      iv4 hv[8];
#pragma unroll
      for (int r = 0; r < 8; ++r)
        hv[r] = *(const iv4*)(hrd + (s & 1) * 128 + 16 * r);

      // prefetch gx for step tt+8 (uniform scalar base + fixed lane index)
      const unsigned short gnext =
          gxh[(size_t)(((tt + 8) & (T_LEN - 1)) * 512) + goffh];

      // 32x sdot4, 4 independent chains
      int acc0 = 0, acc1 = 0, acc2 = 0, acc3 = 0;
#pragma unroll
      for (int r = 0; r < 8; ++r) {
        acc0 = __builtin_amdgcn_sdot4(wq[4 * r + 0], hv[r].x, acc0, false);
        acc1 = __builtin_amdgcn_sdot4(wq[4 * r + 1], hv[r].y, acc1, false);
        acc2 = __builtin_amdgcn_sdot4(wq[4 * r + 2], hv[r].z, acc2, false);
        acc3 = __builtin_amdgcn_sdot4(wq[4 * r + 3], hv[r].w, acc3, false);
      }
      const int iacc = (acc0 + acc1) + (acc2 + acc3);

      __half_raw hraw; hraw.x = gpf[s];
      gpf[s] = gnext;
      const float gxf = __half2float(*(__half*)&hraw);

      // this lane's gate activation (1 exp2 + 1 rcp)
      const float pre = fmaf((float)iacc, dq, gxf);
      const float act = fmaf(frcp(1.f + __builtin_amdgcn_exp2f(pre * emul)),
                             selA, selB);
      // quad holds: g=0: sig(i), g=1: sig(f), g=2: tanh(g), g=3: sig(o)

      // quad-DPP gate exchange (no LDS)
      const float tg = qbcast<2>(act);
      const float tp = act * tg;            // lane 0: sig(i)*tanh(g)
      const float p  = qbcast<0>(tp);
      const float f  = qbcast<1>(act);
      c = fmaf(f, c, p);
      const float tc = fmaf(frcp(1.f + __builtin_amdgcn_exp2f(-2.f * LOG2E * c)),
                            2.f, -1.f);     // tanh(c)
      const float o  = qbcast<3>(act);
      const float h  = o * tc;

      // publish h (all 4 quad lanes write the same byte -> collapses)
      hwr[((s + 1) & 1) * 128] = (signed char)(int)rintf(127.f * h);
      LDS_BARRIER();

      // hist store off the critical path (uniform scalar base + lane index)
      hist[(size_t)tt * FDIM + u] = h;
    }
  }
}

// ---------------------------------------------------------------------------
// Phase C: out[t] = 2*sigmoid(W_fc @ h2[t] + b_fc), in place on d_out.
// ---------------------------------------------------------------------------
__global__ __launch_bounds__(512, 2)
void fc_kernel(const float* __restrict__ Wfc, const float* __restrict__ bfc,
               float* __restrict__ io)
{
  __shared__ float hs[64 * FDIM];
  const int tid  = threadIdx.x;
  const int lane = tid & 63;
  const int wave = tid >> 6;
  const int q    = lane & 15;
  const int gl   = lane >> 4;
  const int g    = wave * 4 + gl;           // 0..31

  float w[4][8];
#pragma unroll
  for (int r = 0; r < 4; ++r)
#pragma unroll
    for (int k = 0; k < 8; ++k)
      w[r][k] = Wfc[(4 * g + r) * FDIM + q * 8 + k];
  const float4 bias = ((const float4*)bfc)[g];

  const int t0 = blockIdx.x * 64;
  float4* iog = (float4*)(io + (size_t)t0 * FDIM);
  float4* hs4 = (float4*)hs;
#pragma unroll
  for (int i = 0; i < 4; ++i) hs4[tid + i * 512] = iog[tid + i * 512];
  __syncthreads();          // all reads of this block's rows done before writes

  for (int tt = 0; tt < 64; ++tt) {
    float hv[8];
    const float4* hv4 = (const float4*)(hs + tt * FDIM + q * 8);
    *(float4*)&hv[0] = hv4[0];
    *(float4*)&hv[4] = hv4[1];
    float acc[4];
#pragma unroll
    for (int r = 0; r < 4; ++r) {
      float a = 0.f;
#pragma unroll
      for (int k = 0; k < 8; ++k) a = fmaf(w[r][k], hv[k], a);
      acc[r] = red16(a);
    }
    if (q == 15) {
      float4 o;
      o.x = 2.f * sigmoid_f(acc[0] + bias.x);
      o.y = 2.f * sigmoid_f(acc[1] + bias.y);
      o.z = 2.f * sigmoid_f(acc[2] + bias.z);
      o.w = 2.f * sigmoid_f(acc[3] + bias.w);
      *(float4*)(io + (size_t)(t0 + tt) * FDIM + 4 * g) = o;
    }
  }
}

// ---------------------------------------------------------------------------
extern "C" void kernel_launch(void* const* d_in, const int* in_sizes, int n_in,
                              void* d_out, int out_size, void* d_ws, size_t ws_size,
                              hipStream_t stream) {
  const float* x    = (const float*)d_in[0];
  // d_in[1..2]: h1_0/c1_0  -- layer-1 LSTM never affects the output: skipped.
  const float* h20  = (const float*)d_in[3];
  const float* c20  = (const float*)d_in[4];
  // d_in[5..8]: W_ih1/W_hh1/b_ih1/b_hh1 -- dead.
  const float* Wih2 = (const float*)d_in[9];
  const float* Whh2 = (const float*)d_in[10];
  const float* bih2 = (const float*)d_in[11];
  const float* bhh2 = (const float*)d_in[12];
  const float* Wfc  = (const float*)d_in[13];
  const float* bfc  = (const float*)d_in[14];

  float*  out = (float*)d_out;              // [T,128]: h2 history, then final out
  __half* gx  = (__half*)d_ws;              // [T][128][4] f16 gate quads (64 MB)

  gx_kernel<<<T_LEN / 64, 512, 0, stream>>>(x, Wih2, bih2, bhh2, gx);
  scan_kernel<<<1, 512, 0, stream>>>(gx, Whh2, h20, c20, out);
  fc_kernel<<<T_LEN / 64, 512, 0, stream>>>(Wfc, bfc, out);
}

// Round 8
// 24525.743 us; speedup vs baseline: 1.2000x; 1.2000x over previous
//
#include <hip/hip_runtime.h>
#include <hip/hip_fp16.h>

#define T_LEN 65536
#define FDIM  128
#define NGATE 512   // 4*F for layer-2 LSTM

typedef int iv4 __attribute__((ext_vector_type(4)));

// ---------- fast math helpers ----------
__device__ __forceinline__ float frcp(float x) { return __builtin_amdgcn_rcpf(x); }
#define LOG2E 1.4426950408889634f
__device__ __forceinline__ float sigmoid_f(float x) {
  return frcp(1.f + __builtin_amdgcn_exp2f(-LOG2E * x));
}

// ---------- DPP cross-lane ops ----------
template<int CTRL, int ROWM, int BANKM, bool BC>
__device__ __forceinline__ float dpp_mov0(float x) {
  return __int_as_float(
      __builtin_amdgcn_update_dpp(0, __float_as_int(x), CTRL, ROWM, BANKM, BC));
}
// xor-1 pair swap within quads: quad_perm(1,0,3,2)
__device__ __forceinline__ float xor1(float x) {
  return dpp_mov0<0xB1, 0xF, 0xF, true>(x);
}
__device__ __forceinline__ float red8(float a) {
  a += dpp_mov0<0xB1, 0xF, 0xF, true>(a);   // quad_perm xor-1
  a += dpp_mov0<0x4E, 0xF, 0xF, true>(a);   // quad_perm xor-2
  a += dpp_mov0<0x114, 0xF, 0xA, true>(a);  // row_shr:4, banks 1&3
  return a;
}
__device__ __forceinline__ float red16(float a) {
  a += dpp_mov0<0x111, 0xF, 0xF, true>(a);
  a += dpp_mov0<0x112, 0xF, 0xF, true>(a);
  a += dpp_mov0<0x114, 0xF, 0xF, true>(a);
  a += dpp_mov0<0x118, 0xF, 0xF, true>(a);
  return a;
}

union H8 { uint4 u; __half h[8]; };
union G2 { unsigned u; __half h[2]; };

// barrier draining ONLY lgkm (LDS): no per-step vmcnt round-trip.
#define LDS_BARRIER() asm volatile("s_waitcnt lgkmcnt(0)\n\ts_barrier" ::: "memory")

// ---------------------------------------------------------------------------
// Phase A: per-unit gate precompute, stored as [T][128] x {i,f,g,o} f16 quads.
// ---------------------------------------------------------------------------
__global__ __launch_bounds__(512, 2)
void gx_kernel(const float* __restrict__ x, const float* __restrict__ Wih2,
               const float* __restrict__ bih2, const float* __restrict__ bhh2,
               __half* __restrict__ gx)
{
  __shared__ float xs[64 * FDIM];           // 32 KB tile of x
  const int tid  = threadIdx.x;
  const int lane = tid & 63;
  const int wave = tid >> 6;
  const int q    = lane & 7;
  const int pl   = lane >> 3;
  const int p    = wave * 8 + pl;
  const int u0   = 2 * p;

  float w[8][16];
  float bias[8];
#pragma unroll
  for (int j = 0; j < 8; ++j) {
    const int row = ((j >> 1) * 128) + u0 + (j & 1);   // j = {i0,i1,f0,f1,g0,g1,o0,o1}
    const int base = row * FDIM + q * 16;
#pragma unroll
    for (int k = 0; k < 16; ++k) w[j][k] = Wih2[base + k];
    bias[j] = bih2[row] + bhh2[row];
  }

  const int t0 = blockIdx.x * 64;
  const float4* xg = (const float4*)(x + (size_t)t0 * FDIM);
  float4* xs4 = (float4*)xs;
#pragma unroll
  for (int i = 0; i < 4; ++i) xs4[tid + i * 512] = xg[tid + i * 512];
  __syncthreads();

  for (int tt = 0; tt < 64; ++tt) {
    float hv[16];
    const float4* hv4 = (const float4*)(xs + tt * FDIM + q * 16);
    *(float4*)&hv[0]  = hv4[0];
    *(float4*)&hv[4]  = hv4[1];
    *(float4*)&hv[8]  = hv4[2];
    *(float4*)&hv[12] = hv4[3];

    float acc[8];
#pragma unroll
    for (int j = 0; j < 8; ++j) {
      float a = 0.f;
#pragma unroll
      for (int k = 0; k < 16; ++k) a = fmaf(w[j][k], hv[k], a);
      acc[j] = red8(a) + bias[j];
    }
    if (q == 4) {
      // store unit-major gate quads: unit u0 -> {i0,f0,g0,o0}, u0+1 -> {i1,f1,g1,o1}
      H8 pk;
      pk.h[0] = __float2half(acc[0]); pk.h[1] = __float2half(acc[2]);
      pk.h[2] = __float2half(acc[4]); pk.h[3] = __float2half(acc[6]);
      pk.h[4] = __float2half(acc[1]); pk.h[5] = __float2half(acc[3]);
      pk.h[6] = __float2half(acc[5]); pk.h[7] = __float2half(acc[7]);
      *((uint4*)(gx + ((size_t)(t0 + tt) * FDIM + u0) * 4)) = pk.u;
    }
  }
}

// ---------------------------------------------------------------------------
// Phase B: sequential LSTM-2 scan, int8 sdot4, 4 waves (1/SIMD), 256 thr.
//   lane = 2*ul + p : pair = unit u = 32*wave + ul; p=0 owns rows {i,f},
//   p=1 owns rows {g,o} (2 full W_hh2 rows per lane, 64 dwords int8).
// Exchange: xor-1 DPP pair swap + cndmask (tp identical on both lanes).
// Body structure kept from round 6 (interleaved ds_read/sdot, dynamic
// double-buffer addressing, hist store BEFORE the lgkm-only barrier) --
// round 7 showed those are load-bearing. Change vs R6: 8 waves -> 4
// (halves barrier resync cost, removes same-SIMD lockstep contention).
// ---------------------------------------------------------------------------
__global__ __launch_bounds__(256)
void scan_kernel(const __half* __restrict__ gx, const float* __restrict__ Whh2,
                 const float* __restrict__ h20, const float* __restrict__ c20,
                 float* __restrict__ hist)
{
  __shared__ __align__(16) signed char hq[2][FDIM];   // int8 h, double-buffered

  const int tid  = threadIdx.x;
  const int lane = tid & 63;
  const int wave = tid >> 6;        // 0..3
  const int p    = lane & 1;        // 0: rows {i,f}, 1: rows {g,o}
  const int ul   = lane >> 1;       // 0..31
  const int u    = 32 * wave + ul;  // 0..127

  // ---- init: quantize this lane's TWO W_hh2 rows to int8, per-row scale ----
  int   wq[2][32];
  float dq[2];
#pragma unroll
  for (int rsel = 0; rsel < 2; ++rsel) {
    const int row = (2 * p + rsel) * FDIM + u;   // gates: p0->{i,f}, p1->{g,o}
    const float* wr = Whh2 + (size_t)row * FDIM;
    float m = 1e-20f;
#pragma unroll
    for (int k = 0; k < FDIM; k += 4) {
      const float4 v = *(const float4*)(wr + k);
      m = fmaxf(m, fmaxf(fmaxf(fabsf(v.x), fabsf(v.y)),
                         fmaxf(fabsf(v.z), fabsf(v.w))));
    }
    const float inv = 127.f / m;
    dq[rsel] = m * (1.f / 16129.f);   // m/127 * 1/127
#pragma unroll
    for (int d = 0; d < 32; ++d) {
      const float4 v = *(const float4*)(wr + 4 * d);
      int b0 = (int)rintf(v.x * inv), b1 = (int)rintf(v.y * inv);
      int b2 = (int)rintf(v.z * inv), b3 = (int)rintf(v.w * inv);
      b0 = b0 < -127 ? -127 : (b0 > 127 ? 127 : b0);
      b1 = b1 < -127 ? -127 : (b1 > 127 ? 127 : b1);
      b2 = b2 < -127 ? -127 : (b2 > 127 ? 127 : b2);
      b3 = b3 < -127 ? -127 : (b3 > 127 ? 127 : b3);
      wq[rsel][d] = (b0 & 255) | ((b1 & 255) << 8) |
                    ((b2 & 255) << 16) | ((b3 & 255) << 24);
    }
  }

  // activation constants: row0 of p=1 is the g-gate -> tanh = 2*sig(2x)-1
  const float emul0 = p ? (-2.f * LOG2E) : (-LOG2E);
  const float selA0 = p ? 2.f : 1.f;
  const float selB0 = p ? -1.f : 0.f;

  float c = c20[u];                 // identical across the lane pair
  if (tid < FDIM) {
    const float hv = fminf(fmaxf(h20[tid], -1.f), 1.f);
    hq[0][tid] = (signed char)(int)rintf(127.f * hv);
  }

  const char* gxb = (const char*)gx;        // step stride: 128 units * 8 B
  const int goff  = u * 8 + p * 4;          // this lane's two gate halves
  unsigned gpf[8];
#pragma unroll
  for (int s = 0; s < 8; ++s)
    gpf[s] = *(const unsigned*)(gxb + (size_t)s * 1024 + goff);

  __syncthreads();

  for (int t = 0; t < T_LEN; t += 8) {
#pragma unroll
    for (int s = 0; s < 8; ++s) {
      const int tt = t + s;
      const signed char* hrow = hq[tt & 1];

      // 64x sdot4 in 8 independent chains; ds_read interleaved with compute
      int a0 = 0, a1 = 0, a2 = 0, a3 = 0;   // row 0
      int b0 = 0, b1 = 0, b2 = 0, b3 = 0;   // row 1
#pragma unroll
      for (int r = 0; r < 8; ++r) {
        const iv4 hv = *(const iv4*)(hrow + 16 * r);
        a0 = __builtin_amdgcn_sdot4(wq[0][4 * r + 0], hv.x, a0, false);
        a1 = __builtin_amdgcn_sdot4(wq[0][4 * r + 1], hv.y, a1, false);
        a2 = __builtin_amdgcn_sdot4(wq[0][4 * r + 2], hv.z, a2, false);
        a3 = __builtin_amdgcn_sdot4(wq[0][4 * r + 3], hv.w, a3, false);
        b0 = __builtin_amdgcn_sdot4(wq[1][4 * r + 0], hv.x, b0, false);
        b1 = __builtin_amdgcn_sdot4(wq[1][4 * r + 1], hv.y, b1, false);
        b2 = __builtin_amdgcn_sdot4(wq[1][4 * r + 2], hv.z, b2, false);
        b3 = __builtin_amdgcn_sdot4(wq[1][4 * r + 3], hv.w, b3, false);
      }
      const int ia0 = (a0 + a1) + (a2 + a3);
      const int ia1 = (b0 + b1) + (b2 + b3);

      G2 g2; g2.u = gpf[s];
      gpf[s] = *(const unsigned*)(
          gxb + (size_t)((tt + 8) & (T_LEN - 1)) * 1024 + goff);

      // pre-activations and this lane's two gate activations
      const float pre0 = fmaf((float)ia0, dq[0], __half2float(g2.h[0]));
      const float pre1 = fmaf((float)ia1, dq[1], __half2float(g2.h[1]));
      const float act0 = fmaf(frcp(1.f + __builtin_amdgcn_exp2f(pre0 * emul0)),
                              selA0, selB0);            // p0: sig(i)  p1: tanh(g)
      const float act1 = frcp(1.f + __builtin_amdgcn_exp2f(pre1 * -LOG2E));
                                                        // p0: sig(f)  p1: sig(o)
      // pair exchange via xor-1 DPP
      const float x0 = xor1(act0);          // p0: tanh(g)   p1: sig(i)
      const float tp = act0 * x0;           // sig(i)*tanh(g) on BOTH lanes
      const float x1 = xor1(act1);          // p0: sig(o)    p1: sig(f)
      const float fv = p ? x1 : act1;       // sig(f) on both
      const float ov = p ? act1 : x1;       // sig(o) on both
      c = fmaf(fv, c, tp);
      const float tc = fmaf(frcp(1.f + __builtin_amdgcn_exp2f(-2.f * LOG2E * c)),
                            2.f, -1.f);     // tanh(c)
      const float h = ov * tc;

      // publish h (both pair lanes write the same byte -> collapses)
      hq[(tt + 1) & 1][u] = (signed char)(int)rintf(127.f * h);
      hist[(size_t)tt * FDIM + u] = h;      // fire-and-forget, pre-barrier
      LDS_BARRIER();
    }
  }
}

// ---------------------------------------------------------------------------
// Phase C: out[t] = 2*sigmoid(W_fc @ h2[t] + b_fc), in place on d_out.
// ---------------------------------------------------------------------------
__global__ __launch_bounds__(512, 2)
void fc_kernel(const float* __restrict__ Wfc, const float* __restrict__ bfc,
               float* __restrict__ io)
{
  __shared__ float hs[64 * FDIM];
  const int tid  = threadIdx.x;
  const int lane = tid & 63;
  const int wave = tid >> 6;
  const int q    = lane & 15;
  const int gl   = lane >> 4;
  const int g    = wave * 4 + gl;           // 0..31

  float w[4][8];
#pragma unroll
  for (int r = 0; r < 4; ++r)
#pragma unroll
    for (int k = 0; k < 8; ++k)
      w[r][k] = Wfc[(4 * g + r) * FDIM + q * 8 + k];
  const float4 bias = ((const float4*)bfc)[g];

  const int t0 = blockIdx.x * 64;
  float4* iog = (float4*)(io + (size_t)t0 * FDIM);
  float4* hs4 = (float4*)hs;
#pragma unroll
  for (int i = 0; i < 4; ++i) hs4[tid + i * 512] = iog[tid + i * 512];
  __syncthreads();          // all reads of this block's rows done before writes

  for (int tt = 0; tt < 64; ++tt) {
    float hv[8];
    const float4* hv4 = (const float4*)(hs + tt * FDIM + q * 8);
    *(float4*)&hv[0] = hv4[0];
    *(float4*)&hv[4] = hv4[1];
    float acc[4];
#pragma unroll
    for (int r = 0; r < 4; ++r) {
      float a = 0.f;
#pragma unroll
      for (int k = 0; k < 8; ++k) a = fmaf(w[r][k], hv[k], a);
      acc[r] = red16(a);
    }
    if (q == 15) {
      float4 o;
      o.x = 2.f * sigmoid_f(acc[0] + bias.x);
      o.y = 2.f * sigmoid_f(acc[1] + bias.y);
      o.z = 2.f * sigmoid_f(acc[2] + bias.z);
      o.w = 2.f * sigmoid_f(acc[3] + bias.w);
      *(float4*)(io + (size_t)(t0 + tt) * FDIM + 4 * g) = o;
    }
  }
}

// ---------------------------------------------------------------------------
extern "C" void kernel_launch(void* const* d_in, const int* in_sizes, int n_in,
                              void* d_out, int out_size, void* d_ws, size_t ws_size,
                              hipStream_t stream) {
  const float* x    = (const float*)d_in[0];
  // d_in[1..2]: h1_0/c1_0  -- layer-1 LSTM never affects the output: skipped.
  const float* h20  = (const float*)d_in[3];
  const float* c20  = (const float*)d_in[4];
  // d_in[5..8]: W_ih1/W_hh1/b_ih1/b_hh1 -- dead.
  const float* Wih2 = (const float*)d_in[9];
  const float* Whh2 = (const float*)d_in[10];
  const float* bih2 = (const float*)d_in[11];
  const float* bhh2 = (const float*)d_in[12];
  const float* Wfc  = (const float*)d_in[13];
  const float* bfc  = (const float*)d_in[14];

  float*  out = (float*)d_out;              // [T,128]: h2 history, then final out
  __half* gx  = (__half*)d_ws;              // [T][128][4] f16 gate quads (64 MB)

  gx_kernel<<<T_LEN / 64, 512, 0, stream>>>(x, Wih2, bih2, bhh2, gx);
  scan_kernel<<<1, 256, 0, stream>>>(gx, Whh2, h20, c20, out);
  fc_kernel<<<T_LEN / 64, 512, 0, stream>>>(Wfc, bfc, out);
}

// Round 9
// 19362.187 us; speedup vs baseline: 1.5200x; 1.2667x over previous
//
#include <hip/hip_runtime.h>
#include <hip/hip_fp16.h>

#define T_LEN 65536
#define FDIM  128
#define NGATE 512   // 4*F for layer-2 LSTM
#define CH    16    // scan chunk (steps per LDS staging buffer)

typedef int iv4 __attribute__((ext_vector_type(4)));

// ---------- fast math helpers ----------
__device__ __forceinline__ float frcp(float x) { return __builtin_amdgcn_rcpf(x); }
#define LOG2E 1.4426950408889634f
__device__ __forceinline__ float sigmoid_f(float x) {
  return frcp(1.f + __builtin_amdgcn_exp2f(-LOG2E * x));
}
__device__ __forceinline__ float tanh_f(float x) {
  return 1.f - 2.f * frcp(__builtin_amdgcn_exp2f(2.f * LOG2E * x) + 1.f);
}

// ---------- DPP cross-lane reduce (Phase A/C only) ----------
template<int CTRL, int ROWM, int BANKM, bool BC>
__device__ __forceinline__ float dpp_mov0(float x) {
  return __int_as_float(
      __builtin_amdgcn_update_dpp(0, __float_as_int(x), CTRL, ROWM, BANKM, BC));
}
__device__ __forceinline__ float red8(float a) {
  a += dpp_mov0<0xB1, 0xF, 0xF, true>(a);   // quad_perm xor-1
  a += dpp_mov0<0x4E, 0xF, 0xF, true>(a);   // quad_perm xor-2
  a += dpp_mov0<0x114, 0xF, 0xA, true>(a);  // row_shr:4, banks 1&3
  return a;
}
__device__ __forceinline__ float red16(float a) {
  a += dpp_mov0<0x111, 0xF, 0xF, true>(a);
  a += dpp_mov0<0x112, 0xF, 0xF, true>(a);
  a += dpp_mov0<0x114, 0xF, 0xF, true>(a);
  a += dpp_mov0<0x118, 0xF, 0xF, true>(a);
  return a;
}

union H8  { uint4 u; __half h[8]; };
union G2u { uint2 u2; __half h[4]; };

// barrier draining ONLY lgkm (LDS): no per-step vmcnt round-trip.
#define LDS_BARRIER() asm volatile("s_waitcnt lgkmcnt(0)\n\ts_barrier" ::: "memory")

// ---------------------------------------------------------------------------
// Phase A: per-unit gate precompute, stored as [T][128] x {i,f,g,o} f16 quads.
// ---------------------------------------------------------------------------
__global__ __launch_bounds__(512, 2)
void gx_kernel(const float* __restrict__ x, const float* __restrict__ Wih2,
               const float* __restrict__ bih2, const float* __restrict__ bhh2,
               __half* __restrict__ gx)
{
  __shared__ float xs[64 * FDIM];           // 32 KB tile of x
  const int tid  = threadIdx.x;
  const int lane = tid & 63;
  const int wave = tid >> 6;
  const int q    = lane & 7;
  const int pl   = lane >> 3;
  const int p    = wave * 8 + pl;
  const int u0   = 2 * p;

  float w[8][16];
  float bias[8];
#pragma unroll
  for (int j = 0; j < 8; ++j) {
    const int row = ((j >> 1) * 128) + u0 + (j & 1);   // j = {i0,i1,f0,f1,g0,g1,o0,o1}
    const int base = row * FDIM + q * 16;
#pragma unroll
    for (int k = 0; k < 16; ++k) w[j][k] = Wih2[base + k];
    bias[j] = bih2[row] + bhh2[row];
  }

  const int t0 = blockIdx.x * 64;
  const float4* xg = (const float4*)(x + (size_t)t0 * FDIM);
  float4* xs4 = (float4*)xs;
#pragma unroll
  for (int i = 0; i < 4; ++i) xs4[tid + i * 512] = xg[tid + i * 512];
  __syncthreads();

  for (int tt = 0; tt < 64; ++tt) {
    float hv[16];
    const float4* hv4 = (const float4*)(xs + tt * FDIM + q * 16);
    *(float4*)&hv[0]  = hv4[0];
    *(float4*)&hv[4]  = hv4[1];
    *(float4*)&hv[8]  = hv4[2];
    *(float4*)&hv[12] = hv4[3];

    float acc[8];
#pragma unroll
    for (int j = 0; j < 8; ++j) {
      float a = 0.f;
#pragma unroll
      for (int k = 0; k < 16; ++k) a = fmaf(w[j][k], hv[k], a);
      acc[j] = red8(a) + bias[j];
    }
    if (q == 4) {
      // store unit-major gate quads: unit u0 -> {i0,f0,g0,o0}, u0+1 -> {i1,f1,g1,o1}
      H8 pk;
      pk.h[0] = __float2half(acc[0]); pk.h[1] = __float2half(acc[2]);
      pk.h[2] = __float2half(acc[4]); pk.h[3] = __float2half(acc[6]);
      pk.h[4] = __float2half(acc[1]); pk.h[5] = __float2half(acc[3]);
      pk.h[6] = __float2half(acc[5]); pk.h[7] = __float2half(acc[7]);
      *((uint4*)(gx + ((size_t)(t0 + tt) * FDIM + u0) * 4)) = pk.u;
    }
  }
}

// ---------------------------------------------------------------------------
// Phase B: sequential LSTM-2 scan, int8 MFMA (R4 engine) with all per-step
// global VMEM removed. 256 threads, 4 waves (1/SIMD).
//   Dot on the MATRIX pipe (separate from VALU): wave w owns units 32w..+31
//   via two 16-col chains; mfma_i32_16x16x64_i8, broadcast-A (all rows = h),
//   W_hh2 int8 B-fragments resident in VGPRs, exact int32 accumulate,
//   per-row dequant scales (bit-identical quant math to rounds 4-8).
// Steady-state step: 2x ds_read_b128 (h) + 1x ds_read_b64 (gx from LDS) +
//   16 MFMA + gate tail + ds_write_b8 (h) + ds_write_b32 (hist) + lgkm barrier.
// Chunked staging (CH=16 steps): gx prefetched chunk-ahead into registers
//   (4x global_load_dwordx4 at chunk top) and relayed to a double-buffered
//   LDS region at chunk end (loads long complete -> no stall); hist batched
//   in LDS and flushed to global once per chunk (fire-and-forget).
// ---------------------------------------------------------------------------
__global__ __launch_bounds__(256)
void scan_kernel(const __half* __restrict__ gx, const float* __restrict__ Whh2,
                 const float* __restrict__ h20, const float* __restrict__ c20,
                 float* __restrict__ hist)
{
  __shared__ __align__(16) signed char hq[2][FDIM];     // 256 B  int8 h
  __shared__ __align__(16) char  gxl[2][CH * 1024];     // 32 KB staged gates
  __shared__ __align__(16) float histb[2][CH * FDIM];   // 16 KB h history

  const int tid  = threadIdx.x;
  const int lane = tid & 63;
  const int wave = tid >> 6;      // 0..3
  const int n    = lane & 15;     // MFMA column
  const int jg   = lane >> 4;     // k-subgroup (0..3)
  const int X    = jg & 1;        // which chain this lane's gate-math uses
  const int ul   = lane & 31;
  const int u    = 32 * wave + ul;   // unit for gate math (lanes 32-63 duplicate)

  // ---- init pass 1: per-row |W| maxima (scratch overlays histb[0]) ----
  float* smax = &histb[0][0];                 // 2048 floats = 8 KB
#pragma unroll
  for (int Xc = 0; Xc < 2; ++Xc) {
    const int urow = 32 * wave + 16 * Xc + n;
#pragma unroll
    for (int g = 0; g < 4; ++g) {
      const float* wr = Whh2 + (size_t)(g * FDIM + urow) * FDIM + 16 * jg;
      float m = 0.f;
#pragma unroll
      for (int kc = 0; kc < 2; ++kc)
#pragma unroll
        for (int j = 0; j < 16; ++j)
          m = fmaxf(m, fabsf(wr[64 * kc + j]));
      smax[((((wave * 2 + Xc) * 4 + g) * 16) + n) * 4 + jg] = m;
    }
  }
  __syncthreads();

  // ---- init pass 2: quantize W into resident int8 B-fragments ----
  iv4 bq[2][4][2];          // [chain X][gate][k-chunk], 16 bytes each
  float scC[2][4];          // dequant scales per chain/gate
#pragma unroll
  for (int Xc = 0; Xc < 2; ++Xc) {
    const int urow = 32 * wave + 16 * Xc + n;
#pragma unroll
    for (int g = 0; g < 4; ++g) {
      const int rowid = (((wave * 2 + Xc) * 4 + g) * 16) + n;
      float s = fmaxf(fmaxf(smax[rowid * 4 + 0], smax[rowid * 4 + 1]),
                      fmaxf(smax[rowid * 4 + 2], smax[rowid * 4 + 3]));
      s = fmaxf(s, 1e-20f);
      scC[Xc][g] = s * (1.f / 16129.f);    // s/127 * 1/127
      const float inv = 127.f / s;
      const float* wr = Whh2 + (size_t)(g * FDIM + urow) * FDIM + 16 * jg;
#pragma unroll
      for (int kc = 0; kc < 2; ++kc) {
        iv4 frag;
#pragma unroll
        for (int r = 0; r < 4; ++r) {
          int packed = 0;
#pragma unroll
          for (int b = 0; b < 4; ++b) {
            int qv = (int)rintf(wr[64 * kc + 4 * r + b] * inv);
            qv = qv < -127 ? -127 : (qv > 127 ? 127 : qv);
            packed |= (qv & 255) << (8 * b);
          }
          frag[r] = packed;
        }
        bq[Xc][g][kc] = frag;
      }
    }
  }

  // per-lane dequant scale for this lane's gate-math chain
  float scl[4];
#pragma unroll
  for (int g = 0; g < 4; ++g) scl[g] = X ? scC[1][g] : scC[0][g];

  float c = c20[u];
  if (tid < FDIM) {
    const float hv = fminf(fmaxf(h20[tid], -1.f), 1.f);
    hq[0][tid] = (signed char)(int)rintf(127.f * hv);
  }

  // preload gx chunk 0 into gxl[0]
  const uint4* gglob = (const uint4*)gx;      // 1024 uint4 per chunk
  {
#pragma unroll
    for (int r = 0; r < 4; ++r) {
      const uint4 v = gglob[r * 256 + tid];
      *(uint4*)(&gxl[0][r * 4096 + tid * 16]) = v;
    }
  }

  const iv4 zero = {0, 0, 0, 0};
  __syncthreads();        // seals smax scratch, hq[0], gxl[0]

  for (int t4 = 0; t4 < T_LEN; t4 += CH) {
    const int chunk = t4 >> 4;
    const int buf   = chunk & 1;

    // prefetch next gx chunk into registers (relayed to LDS at chunk end)
    const int nchunk = (chunk + 1) & (T_LEN / CH - 1);
    const uint4 pf0 = gglob[(size_t)nchunk * 1024 + 0 * 256 + tid];
    const uint4 pf1 = gglob[(size_t)nchunk * 1024 + 1 * 256 + tid];
    const uint4 pf2 = gglob[(size_t)nchunk * 1024 + 2 * 256 + tid];
    const uint4 pf3 = gglob[(size_t)nchunk * 1024 + 3 * 256 + tid];

    // flush previous chunk's h history (fire-and-forget)
    if (t4 != 0) {
      float* gdst = hist + (size_t)(t4 - CH) * FDIM;
      const float* hsb = &histb[1 - buf][0];
#pragma unroll
      for (int j = 0; j < 2; ++j) {
        const float4 v = *(const float4*)(hsb + 4 * (tid + 256 * j));
        *(float4*)(gdst + 4 * (tid + 256 * j)) = v;
      }
    }

#pragma unroll
    for (int s = 0; s < CH; ++s) {
      // h_{t-1}: 2x ds_read_b128 broadcast; gx: 1x ds_read_b64 from LDS
      const signed char* hrow = hq[s & 1];
      const iv4 a0 = *(const iv4*)(hrow + jg * 16);
      const iv4 a1 = *(const iv4*)(hrow + 64 + jg * 16);
      G2u gg; gg.u2 = *(const uint2*)(&gxl[buf][s * 1024 + u * 8]);

      // 16 MFMA on the matrix pipe (i and g chains first: tail needs them first)
      iv4 acc[2][4];
#pragma unroll
      for (int Xc = 0; Xc < 2; ++Xc) {
        {
          iv4 d = __builtin_amdgcn_mfma_i32_16x16x64_i8(a0, bq[Xc][0][0], zero, 0, 0, 0);
          acc[Xc][0] = __builtin_amdgcn_mfma_i32_16x16x64_i8(a1, bq[Xc][0][1], d, 0, 0, 0);
        }
        {
          iv4 d = __builtin_amdgcn_mfma_i32_16x16x64_i8(a0, bq[Xc][2][0], zero, 0, 0, 0);
          acc[Xc][2] = __builtin_amdgcn_mfma_i32_16x16x64_i8(a1, bq[Xc][2][1], d, 0, 0, 0);
        }
        {
          iv4 d = __builtin_amdgcn_mfma_i32_16x16x64_i8(a0, bq[Xc][1][0], zero, 0, 0, 0);
          acc[Xc][1] = __builtin_amdgcn_mfma_i32_16x16x64_i8(a1, bq[Xc][1][1], d, 0, 0, 0);
        }
        {
          iv4 d = __builtin_amdgcn_mfma_i32_16x16x64_i8(a0, bq[Xc][3][0], zero, 0, 0, 0);
          acc[Xc][3] = __builtin_amdgcn_mfma_i32_16x16x64_i8(a1, bq[Xc][3][1], d, 0, 0, 0);
        }
      }

      // pick this lane's chain (values replicated across rows -> comp 0 valid)
      float dv[4];
#pragma unroll
      for (int g = 0; g < 4; ++g)
        dv[g] = (float)(X ? acc[1][g][0] : acc[0][g][0]);

      const float gi = fmaf(dv[0], scl[0], __half2float(gg.h[0]));
      const float gf = fmaf(dv[1], scl[1], __half2float(gg.h[1]));
      const float ggt = fmaf(dv[2], scl[2], __half2float(gg.h[2]));
      const float go = fmaf(dv[3], scl[3], __half2float(gg.h[3]));

      c = sigmoid_f(gf) * c + sigmoid_f(gi) * tanh_f(ggt);
      const float h = sigmoid_f(go) * tanh_f(c);

      // publish (lane pairs write identical values to the same address)
      hq[(s + 1) & 1][u] = (signed char)(int)rintf(127.f * h);
      histb[buf][s * FDIM + u] = h;

      if (s == CH - 1) {    // relay prefetched gx into the other LDS buffer
        *(uint4*)(&gxl[1 - buf][0 * 4096 + tid * 16]) = pf0;
        *(uint4*)(&gxl[1 - buf][1 * 4096 + tid * 16]) = pf1;
        *(uint4*)(&gxl[1 - buf][2 * 4096 + tid * 16]) = pf2;
        *(uint4*)(&gxl[1 - buf][3 * 4096 + tid * 16]) = pf3;
      }
      LDS_BARRIER();
    }
  }

  // final hist chunk flush (sealed by the loop's last barrier)
  {
    float* gdst = hist + (size_t)(T_LEN - CH) * FDIM;
    const float* hsb = &histb[1][0];
#pragma unroll
    for (int j = 0; j < 2; ++j) {
      const float4 v = *(const float4*)(hsb + 4 * (tid + 256 * j));
      *(float4*)(gdst + 4 * (tid + 256 * j)) = v;
    }
  }
}

// ---------------------------------------------------------------------------
// Phase C: out[t] = 2*sigmoid(W_fc @ h2[t] + b_fc), in place on d_out.
// ---------------------------------------------------------------------------
__global__ __launch_bounds__(512, 2)
void fc_kernel(const float* __restrict__ Wfc, const float* __restrict__ bfc,
               float* __restrict__ io)
{
  __shared__ float hs[64 * FDIM];
  const int tid  = threadIdx.x;
  const int lane = tid & 63;
  const int wave = tid >> 6;
  const int q    = lane & 15;
  const int gl   = lane >> 4;
  const int g    = wave * 4 + gl;           // 0..31

  float w[4][8];
#pragma unroll
  for (int r = 0; r < 4; ++r)
#pragma unroll
    for (int k = 0; k < 8; ++k)
      w[r][k] = Wfc[(4 * g + r) * FDIM + q * 8 + k];
  const float4 bias = ((const float4*)bfc)[g];

  const int t0 = blockIdx.x * 64;
  float4* iog = (float4*)(io + (size_t)t0 * FDIM);
  float4* hs4 = (float4*)hs;
#pragma unroll
  for (int i = 0; i < 4; ++i) hs4[tid + i * 512] = iog[tid + i * 512];
  __syncthreads();          // all reads of this block's rows done before writes

  for (int tt = 0; tt < 64; ++tt) {
    float hv[8];
    const float4* hv4 = (const float4*)(hs + tt * FDIM + q * 8);
    *(float4*)&hv[0] = hv4[0];
    *(float4*)&hv[4] = hv4[1];
    float acc[4];
#pragma unroll
    for (int r = 0; r < 4; ++r) {
      float a = 0.f;
#pragma unroll
      for (int k = 0; k < 8; ++k) a = fmaf(w[r][k], hv[k], a);
      acc[r] = red16(a);
    }
    if (q == 15) {
      float4 o;
      o.x = 2.f * sigmoid_f(acc[0] + bias.x);
      o.y = 2.f * sigmoid_f(acc[1] + bias.y);
      o.z = 2.f * sigmoid_f(acc[2] + bias.z);
      o.w = 2.f * sigmoid_f(acc[3] + bias.w);
      *(float4*)(io + (size_t)(t0 + tt) * FDIM + 4 * g) = o;
    }
  }
}

// ---------------------------------------------------------------------------
extern "C" void kernel_launch(void* const* d_in, const int* in_sizes, int n_in,
                              void* d_out, int out_size, void* d_ws, size_t ws_size,
                              hipStream_t stream) {
  const float* x    = (const float*)d_in[0];
  // d_in[1..2]: h1_0/c1_0  -- layer-1 LSTM never affects the output: skipped.
  const float* h20  = (const float*)d_in[3];
  const float* c20  = (const float*)d_in[4];
  // d_in[5..8]: W_ih1/W_hh1/b_ih1/b_hh1 -- dead.
  const float* Wih2 = (const float*)d_in[9];
  const float* Whh2 = (const float*)d_in[10];
  const float* bih2 = (const float*)d_in[11];
  const float* bhh2 = (const float*)d_in[12];
  const float* Wfc  = (const float*)d_in[13];
  const float* bfc  = (const float*)d_in[14];

  float*  out = (float*)d_out;              // [T,128]: h2 history, then final out
  __half* gx  = (__half*)d_ws;              // [T][128][4] f16 gate quads (64 MB)

  gx_kernel<<<T_LEN / 64, 512, 0, stream>>>(x, Wih2, bih2, bhh2, gx);
  scan_kernel<<<1, 256, 0, stream>>>(gx, Whh2, h20, c20, out);
  fc_kernel<<<T_LEN / 64, 512, 0, stream>>>(Wfc, bfc, out);
}

// Round 10
// 18580.724 us; speedup vs baseline: 1.5839x; 1.0421x over previous
//
#include <hip/hip_runtime.h>
#include <hip/hip_fp16.h>

#define T_LEN 65536
#define FDIM  128
#define NGATE 512   // 4*F for layer-2 LSTM
#define CH    16    // scan chunk (steps per LDS staging buffer)

typedef int iv4 __attribute__((ext_vector_type(4)));

// ---------- fast math helpers ----------
__device__ __forceinline__ float frcp(float x) { return __builtin_amdgcn_rcpf(x); }
#define LOG2E 1.4426950408889634f
__device__ __forceinline__ float sigmoid_f(float x) {
  return frcp(1.f + __builtin_amdgcn_exp2f(-LOG2E * x));
}
__device__ __forceinline__ float tanh_f(float x) {
  return 1.f - 2.f * frcp(__builtin_amdgcn_exp2f(2.f * LOG2E * x) + 1.f);
}

// ---------- DPP cross-lane reduce (Phase A/C only) ----------
template<int CTRL, int ROWM, int BANKM, bool BC>
__device__ __forceinline__ float dpp_mov0(float x) {
  return __int_as_float(
      __builtin_amdgcn_update_dpp(0, __float_as_int(x), CTRL, ROWM, BANKM, BC));
}
__device__ __forceinline__ float red8(float a) {
  a += dpp_mov0<0xB1, 0xF, 0xF, true>(a);   // quad_perm xor-1
  a += dpp_mov0<0x4E, 0xF, 0xF, true>(a);   // quad_perm xor-2
  a += dpp_mov0<0x114, 0xF, 0xA, true>(a);  // row_shr:4, banks 1&3
  return a;
}
__device__ __forceinline__ float red16(float a) {
  a += dpp_mov0<0x111, 0xF, 0xF, true>(a);
  a += dpp_mov0<0x112, 0xF, 0xF, true>(a);
  a += dpp_mov0<0x114, 0xF, 0xF, true>(a);
  a += dpp_mov0<0x118, 0xF, 0xF, true>(a);
  return a;
}

union H8  { uint4 u; __half h[8]; };
union G2u { uint2 u2; __half h[4]; };

// barrier draining ONLY lgkm (LDS): no per-step vmcnt round-trip.
#define LDS_BARRIER() asm volatile("s_waitcnt lgkmcnt(0)\n\ts_barrier" ::: "memory")

// ---------------------------------------------------------------------------
// Phase A: per-unit gate precompute, stored as [T][128] x {i,f,g,o} f16 quads.
// NOTE: stored values are PRE-SCALED by the sigmoid/tanh exp2 multipliers
//   {-log2e, -log2e, -2log2e, -log2e} so the scan's sigmoid argument is a
//   single fma (the dequant scales carry the same factors).
// ---------------------------------------------------------------------------
__global__ __launch_bounds__(512, 2)
void gx_kernel(const float* __restrict__ x, const float* __restrict__ Wih2,
               const float* __restrict__ bih2, const float* __restrict__ bhh2,
               __half* __restrict__ gx)
{
  __shared__ float xs[64 * FDIM];           // 32 KB tile of x
  const int tid  = threadIdx.x;
  const int lane = tid & 63;
  const int wave = tid >> 6;
  const int q    = lane & 7;
  const int pl   = lane >> 3;
  const int p    = wave * 8 + pl;
  const int u0   = 2 * p;

  float w[8][16];
  float bias[8];
#pragma unroll
  for (int j = 0; j < 8; ++j) {
    const int row = ((j >> 1) * 128) + u0 + (j & 1);   // j = {i0,i1,f0,f1,g0,g1,o0,o1}
    const int base = row * FDIM + q * 16;
#pragma unroll
    for (int k = 0; k < 16; ++k) w[j][k] = Wih2[base + k];
    bias[j] = bih2[row] + bhh2[row];
  }

  const int t0 = blockIdx.x * 64;
  const float4* xg = (const float4*)(x + (size_t)t0 * FDIM);
  float4* xs4 = (float4*)xs;
#pragma unroll
  for (int i = 0; i < 4; ++i) xs4[tid + i * 512] = xg[tid + i * 512];
  __syncthreads();

  for (int tt = 0; tt < 64; ++tt) {
    float hv[16];
    const float4* hv4 = (const float4*)(xs + tt * FDIM + q * 16);
    *(float4*)&hv[0]  = hv4[0];
    *(float4*)&hv[4]  = hv4[1];
    *(float4*)&hv[8]  = hv4[2];
    *(float4*)&hv[12] = hv4[3];

    float acc[8];
#pragma unroll
    for (int j = 0; j < 8; ++j) {
      float a = 0.f;
#pragma unroll
      for (int k = 0; k < 16; ++k) a = fmaf(w[j][k], hv[k], a);
      acc[j] = red8(a) + bias[j];
    }
    if (q == 4) {
      // unit-major gate quads, pre-scaled: i,f,o by -L; g by -2L
      const float mL = -LOG2E, m2L = -2.f * LOG2E;
      H8 pk;
      pk.h[0] = __float2half(acc[0] * mL);  pk.h[1] = __float2half(acc[2] * mL);
      pk.h[2] = __float2half(acc[4] * m2L); pk.h[3] = __float2half(acc[6] * mL);
      pk.h[4] = __float2half(acc[1] * mL);  pk.h[5] = __float2half(acc[3] * mL);
      pk.h[6] = __float2half(acc[5] * m2L); pk.h[7] = __float2half(acc[7] * mL);
      *((uint4*)(gx + ((size_t)(t0 + tt) * FDIM + u0) * 4)) = pk.u;
    }
  }
}

// ---------------------------------------------------------------------------
// Phase B: sequential LSTM-2 scan, int8 MFMA, zero per-step global VMEM.
// 256 threads, 4 waves (1/SIMD). Same structure as round 9; deltas:
//  - MFMA emission in two batches of 4 independent leading MFMAs followed by
//    their 4 dependents (no dependent-pair bubbles, bounded VGPR growth).
//  - sigmoid/tanh exp2 multipliers folded into gx (Phase A) and the dequant
//    scales -> sigmoid arg is one fma; 4 serial v_muls removed from the tail.
// ---------------------------------------------------------------------------
__global__ __launch_bounds__(256)
void scan_kernel(const __half* __restrict__ gx, const float* __restrict__ Whh2,
                 const float* __restrict__ h20, const float* __restrict__ c20,
                 float* __restrict__ hist)
{
  __shared__ __align__(16) signed char hq[2][FDIM];     // 256 B  int8 h
  __shared__ __align__(16) char  gxl[2][CH * 1024];     // 32 KB staged gates
  __shared__ __align__(16) float histb[2][CH * FDIM];   // 16 KB h history

  const int tid  = threadIdx.x;
  const int lane = tid & 63;
  const int wave = tid >> 6;      // 0..3
  const int n    = lane & 15;     // MFMA column
  const int jg   = lane >> 4;     // k-subgroup (0..3)
  const int X    = jg & 1;        // which chain this lane's gate-math uses
  const int ul   = lane & 31;
  const int u    = 32 * wave + ul;   // unit for gate math (lanes 32-63 duplicate)

  // ---- init pass 1: per-row |W| maxima (scratch overlays histb[0]) ----
  float* smax = &histb[0][0];                 // 2048 floats = 8 KB
#pragma unroll
  for (int Xc = 0; Xc < 2; ++Xc) {
    const int urow = 32 * wave + 16 * Xc + n;
#pragma unroll
    for (int g = 0; g < 4; ++g) {
      const float* wr = Whh2 + (size_t)(g * FDIM + urow) * FDIM + 16 * jg;
      float m = 0.f;
#pragma unroll
      for (int kc = 0; kc < 2; ++kc)
#pragma unroll
        for (int j = 0; j < 16; ++j)
          m = fmaxf(m, fabsf(wr[64 * kc + j]));
      smax[((((wave * 2 + Xc) * 4 + g) * 16) + n) * 4 + jg] = m;
    }
  }
  __syncthreads();

  // ---- init pass 2: quantize W into resident int8 B-fragments ----
  iv4 bq[2][4][2];          // [chain X][gate][k-chunk], 16 bytes each
  float scC[2][4];          // dequant scales per chain/gate
#pragma unroll
  for (int Xc = 0; Xc < 2; ++Xc) {
    const int urow = 32 * wave + 16 * Xc + n;
#pragma unroll
    for (int g = 0; g < 4; ++g) {
      const int rowid = (((wave * 2 + Xc) * 4 + g) * 16) + n;
      float s = fmaxf(fmaxf(smax[rowid * 4 + 0], smax[rowid * 4 + 1]),
                      fmaxf(smax[rowid * 4 + 2], smax[rowid * 4 + 3]));
      s = fmaxf(s, 1e-20f);
      scC[Xc][g] = s * (1.f / 16129.f);    // s/127 * 1/127
      const float inv = 127.f / s;
      const float* wr = Whh2 + (size_t)(g * FDIM + urow) * FDIM + 16 * jg;
#pragma unroll
      for (int kc = 0; kc < 2; ++kc) {
        iv4 frag;
#pragma unroll
        for (int r = 0; r < 4; ++r) {
          int packed = 0;
#pragma unroll
          for (int b = 0; b < 4; ++b) {
            int qv = (int)rintf(wr[64 * kc + 4 * r + b] * inv);
            qv = qv < -127 ? -127 : (qv > 127 ? 127 : qv);
            packed |= (qv & 255) << (8 * b);
          }
          frag[r] = packed;
        }
        bq[Xc][g][kc] = frag;
      }
    }
  }

  // per-lane dequant scales with the exp2 multipliers folded in
  const float gmul[4] = { -LOG2E, -LOG2E, -2.f * LOG2E, -LOG2E };
  float scl[4];
#pragma unroll
  for (int g = 0; g < 4; ++g) scl[g] = (X ? scC[1][g] : scC[0][g]) * gmul[g];

  float c = c20[u];
  if (tid < FDIM) {
    const float hv = fminf(fmaxf(h20[tid], -1.f), 1.f);
    hq[0][tid] = (signed char)(int)rintf(127.f * hv);
  }

  // preload gx chunk 0 into gxl[0]
  const uint4* gglob = (const uint4*)gx;      // 1024 uint4 per chunk
  {
#pragma unroll
    for (int r = 0; r < 4; ++r) {
      const uint4 v = gglob[r * 256 + tid];
      *(uint4*)(&gxl[0][r * 4096 + tid * 16]) = v;
    }
  }

  const iv4 zero = {0, 0, 0, 0};
  __syncthreads();        // seals smax scratch, hq[0], gxl[0]

  for (int t4 = 0; t4 < T_LEN; t4 += CH) {
    const int chunk = t4 >> 4;
    const int buf   = chunk & 1;

    // prefetch next gx chunk into registers (relayed to LDS at chunk end)
    const int nchunk = (chunk + 1) & (T_LEN / CH - 1);
    const uint4 pf0 = gglob[(size_t)nchunk * 1024 + 0 * 256 + tid];
    const uint4 pf1 = gglob[(size_t)nchunk * 1024 + 1 * 256 + tid];
    const uint4 pf2 = gglob[(size_t)nchunk * 1024 + 2 * 256 + tid];
    const uint4 pf3 = gglob[(size_t)nchunk * 1024 + 3 * 256 + tid];

    // flush previous chunk's h history (fire-and-forget)
    if (t4 != 0) {
      float* gdst = hist + (size_t)(t4 - CH) * FDIM;
      const float* hsb = &histb[1 - buf][0];
#pragma unroll
      for (int j = 0; j < 2; ++j) {
        const float4 v = *(const float4*)(hsb + 4 * (tid + 256 * j));
        *(float4*)(gdst + 4 * (tid + 256 * j)) = v;
      }
    }

#pragma unroll
    for (int s = 0; s < CH; ++s) {
      // h_{t-1}: 2x ds_read_b128 broadcast; gx: 1x ds_read_b64 from LDS
      const signed char* hrow = hq[s & 1];
      const iv4 a0 = *(const iv4*)(hrow + jg * 16);
      const iv4 a1 = *(const iv4*)(hrow + 64 + jg * 16);
      G2u gg; gg.u2 = *(const uint2*)(&gxl[buf][s * 1024 + u * 8]);

      // 16 MFMA in two batches of 4 independent leads + 4 dependents:
      // batch 1 = {i,g} chains (tail needs them first), batch 2 = {f,o}.
      iv4 acc[2][4];
      {
        iv4 d00 = __builtin_amdgcn_mfma_i32_16x16x64_i8(a0, bq[0][0][0], zero, 0, 0, 0);
        iv4 d02 = __builtin_amdgcn_mfma_i32_16x16x64_i8(a0, bq[0][2][0], zero, 0, 0, 0);
        iv4 d10 = __builtin_amdgcn_mfma_i32_16x16x64_i8(a0, bq[1][0][0], zero, 0, 0, 0);
        iv4 d12 = __builtin_amdgcn_mfma_i32_16x16x64_i8(a0, bq[1][2][0], zero, 0, 0, 0);
        acc[0][0] = __builtin_amdgcn_mfma_i32_16x16x64_i8(a1, bq[0][0][1], d00, 0, 0, 0);
        acc[0][2] = __builtin_amdgcn_mfma_i32_16x16x64_i8(a1, bq[0][2][1], d02, 0, 0, 0);
        acc[1][0] = __builtin_amdgcn_mfma_i32_16x16x64_i8(a1, bq[1][0][1], d10, 0, 0, 0);
        acc[1][2] = __builtin_amdgcn_mfma_i32_16x16x64_i8(a1, bq[1][2][1], d12, 0, 0, 0);
      }
      {
        iv4 d01 = __builtin_amdgcn_mfma_i32_16x16x64_i8(a0, bq[0][1][0], zero, 0, 0, 0);
        iv4 d03 = __builtin_amdgcn_mfma_i32_16x16x64_i8(a0, bq[0][3][0], zero, 0, 0, 0);
        iv4 d11 = __builtin_amdgcn_mfma_i32_16x16x64_i8(a0, bq[1][1][0], zero, 0, 0, 0);
        iv4 d13 = __builtin_amdgcn_mfma_i32_16x16x64_i8(a0, bq[1][3][0], zero, 0, 0, 0);
        acc[0][1] = __builtin_amdgcn_mfma_i32_16x16x64_i8(a1, bq[0][1][1], d01, 0, 0, 0);
        acc[0][3] = __builtin_amdgcn_mfma_i32_16x16x64_i8(a1, bq[0][3][1], d03, 0, 0, 0);
        acc[1][1] = __builtin_amdgcn_mfma_i32_16x16x64_i8(a1, bq[1][1][1], d11, 0, 0, 0);
        acc[1][3] = __builtin_amdgcn_mfma_i32_16x16x64_i8(a1, bq[1][3][1], d13, 0, 0, 0);
      }

      // pick this lane's chain (values replicated across rows -> comp 0 valid)
      float dv[4];
#pragma unroll
      for (int g = 0; g < 4; ++g)
        dv[g] = (float)(X ? acc[1][g][0] : acc[0][g][0]);

      // sigmoid args directly via one fma each (multipliers pre-folded)
      const float ai = fmaf(dv[0], scl[0], __half2float(gg.h[0]));
      const float af = fmaf(dv[1], scl[1], __half2float(gg.h[1]));
      const float ag = fmaf(dv[2], scl[2], __half2float(gg.h[2]));
      const float ao = fmaf(dv[3], scl[3], __half2float(gg.h[3]));

      const float si = frcp(1.f + __builtin_amdgcn_exp2f(ai));
      const float tg = fmaf(frcp(1.f + __builtin_amdgcn_exp2f(ag)), 2.f, -1.f);
      const float sf = frcp(1.f + __builtin_amdgcn_exp2f(af));
      const float so = frcp(1.f + __builtin_amdgcn_exp2f(ao));

      c = fmaf(sf, c, si * tg);
      const float tc = fmaf(frcp(1.f + __builtin_amdgcn_exp2f(-2.f * LOG2E * c)),
                            2.f, -1.f);     // tanh(c)
      const float h = so * tc;

      // publish (lane pairs write identical values to the same address)
      hq[(s + 1) & 1][u] = (signed char)(int)rintf(127.f * h);
      histb[buf][s * FDIM + u] = h;

      if (s == CH - 1) {    // relay prefetched gx into the other LDS buffer
        *(uint4*)(&gxl[1 - buf][0 * 4096 + tid * 16]) = pf0;
        *(uint4*)(&gxl[1 - buf][1 * 4096 + tid * 16]) = pf1;
        *(uint4*)(&gxl[1 - buf][2 * 4096 + tid * 16]) = pf2;
        *(uint4*)(&gxl[1 - buf][3 * 4096 + tid * 16]) = pf3;
      }
      LDS_BARRIER();
    }
  }

  // final hist chunk flush (sealed by the loop's last barrier)
  {
    float* gdst = hist + (size_t)(T_LEN - CH) * FDIM;
    const float* hsb = &histb[1][0];
#pragma unroll
    for (int j = 0; j < 2; ++j) {
      const float4 v = *(const float4*)(hsb + 4 * (tid + 256 * j));
      *(float4*)(gdst + 4 * (tid + 256 * j)) = v;
    }
  }
}

// ---------------------------------------------------------------------------
// Phase C: out[t] = 2*sigmoid(W_fc @ h2[t] + b_fc), in place on d_out.
// ---------------------------------------------------------------------------
__global__ __launch_bounds__(512, 2)
void fc_kernel(const float* __restrict__ Wfc, const float* __restrict__ bfc,
               float* __restrict__ io)
{
  __shared__ float hs[64 * FDIM];
  const int tid  = threadIdx.x;
  const int lane = tid & 63;
  const int wave = tid >> 6;
  const int q    = lane & 15;
  const int gl   = lane >> 4;
  const int g    = wave * 4 + gl;           // 0..31

  float w[4][8];
#pragma unroll
  for (int r = 0; r < 4; ++r)
#pragma unroll
    for (int k = 0; k < 8; ++k)
      w[r][k] = Wfc[(4 * g + r) * FDIM + q * 8 + k];
  const float4 bias = ((const float4*)bfc)[g];

  const int t0 = blockIdx.x * 64;
  float4* iog = (float4*)(io + (size_t)t0 * FDIM);
  float4* hs4 = (float4*)hs;
#pragma unroll
  for (int i = 0; i < 4; ++i) hs4[tid + i * 512] = iog[tid + i * 512];
  __syncthreads();          // all reads of this block's rows done before writes

  for (int tt = 0; tt < 64; ++tt) {
    float hv[8];
    const float4* hv4 = (const float4*)(hs + tt * FDIM + q * 8);
    *(float4*)&hv[0] = hv4[0];
    *(float4*)&hv[4] = hv4[1];
    float acc[4];
#pragma unroll
    for (int r = 0; r < 4; ++r) {
      float a = 0.f;
#pragma unroll
      for (int k = 0; k < 8; ++k) a = fmaf(w[r][k], hv[k], a);
      acc[r] = red16(a);
    }
    if (q == 15) {
      float4 o;
      o.x = 2.f * sigmoid_f(acc[0] + bias.x);
      o.y = 2.f * sigmoid_f(acc[1] + bias.y);
      o.z = 2.f * sigmoid_f(acc[2] + bias.z);
      o.w = 2.f * sigmoid_f(acc[3] + bias.w);
      *(float4*)(io + (size_t)(t0 + tt) * FDIM + 4 * g) = o;
    }
  }
}

// ---------------------------------------------------------------------------
extern "C" void kernel_launch(void* const* d_in, const int* in_sizes, int n_in,
                              void* d_out, int out_size, void* d_ws, size_t ws_size,
                              hipStream_t stream) {
  const float* x    = (const float*)d_in[0];
  // d_in[1..2]: h1_0/c1_0  -- layer-1 LSTM never affects the output: skipped.
  const float* h20  = (const float*)d_in[3];
  const float* c20  = (const float*)d_in[4];
  // d_in[5..8]: W_ih1/W_hh1/b_ih1/b_hh1 -- dead.
  const float* Wih2 = (const float*)d_in[9];
  const float* Whh2 = (const float*)d_in[10];
  const float* bih2 = (const float*)d_in[11];
  const float* bhh2 = (const float*)d_in[12];
  const float* Wfc  = (const float*)d_in[13];
  const float* bfc  = (const float*)d_in[14];

  float*  out = (float*)d_out;              // [T,128]: h2 history, then final out
  __half* gx  = (__half*)d_ws;              // [T][128][4] f16 gate quads (64 MB)

  gx_kernel<<<T_LEN / 64, 512, 0, stream>>>(x, Wih2, bih2, bhh2, gx);
  scan_kernel<<<1, 256, 0, stream>>>(gx, Whh2, h20, c20, out);
  fc_kernel<<<T_LEN / 64, 512, 0, stream>>>(Wfc, bfc, out);
}